// Round 20
// baseline (123.279 us; speedup 1.0000x reference)
//
#include <hip/hip_runtime.h>

#define NPIX 49152   // B*H*W = 1*192*256
#define H_ 192
#define W_ 256
#define TPB 64       // tokens per chain block (64 tokens; 256 thr = 4 waves)

// ---------------------------------------------------------------------------
// both weight transposes (32 blocks) + zero binning counters (block 0)
// ---------------------------------------------------------------------------
__global__ __launch_bounds__(256) void wtrans2_k(const float* __restrict__ Wa,
    float* __restrict__ WTa, const float* __restrict__ Wb,
    float* __restrict__ WTb, int* __restrict__ S) {
  const int b = blockIdx.x;
  const float* __restrict__ W = (b < 16) ? Wa : Wb;
  float* __restrict__ WT = (b < 16) ? WTa : WTb;
  const int bb = b & 15;
  __shared__ float tile[32][33];
  const int bx = bb & 3, by = bb >> 2;
  const int c = threadIdx.x & 31, r0 = threadIdx.x >> 5;
#pragma unroll
  for (int j = 0; j < 4; ++j) {
    const int r = r0 + j * 8;
    tile[r][c] = W[(by * 32 + r) * 128 + bx * 32 + c];
  }
  __syncthreads();
#pragma unroll
  for (int j = 0; j < 4; ++j) {
    const int r = r0 + j * 8;
    WT[(bx * 32 + r) * 128 + by * 32 + c] = tile[c][r];
  }
  if (b == 0) {
    const int t = threadIdx.x;
    if (t < 32) S[t] = 0;        // cnt1 + cur1
    S[1088 + t] = 0;             // cnt2
    S[1344 + t] = 0;             // cur2
  }
}

// ---------------------------------------------------------------------------
// FUSED conv1 + conv2 + conv17 + argmax + mask + histogram + x transpose.
// v2: 128-pixel tile, 2 px/lane -> 32 FMA per 64B of scalar weights (1 B/cy
// demand, under the ~1.3 B/cy scalar-prefetch ceiling). Half-k LDS buffer
// (k 0..63 then 64..127) keeps static LDS at 43.4 KB. All accumulators stay
// bias-then-k-ascending with identical values -> bitwise identical outputs.
// ---------------------------------------------------------------------------
__global__ __launch_bounds__(512) void convfused_k(const float* __restrict__ X,
    const float* __restrict__ WT1, const float* __restrict__ Bv1,
    const float* __restrict__ WT2, const float* __restrict__ Bv2,
    const float* __restrict__ W3, const float* __restrict__ Bv3,
    unsigned char* __restrict__ inds1, float* __restrict__ mask_out,
    int* __restrict__ cnt1, float* __restrict__ xt) {
  __shared__ float xbuf[64][130];  // 33.3 KB: half-k raw x / activations
  __shared__ float w3s[128 * 20];  // 10 KB W3 [k][20]
  __shared__ int lh[16];
  const int t = threadIdx.x;
  const int lane = t & 63;
  const int wv = t >> 6;           // wave id 0..7 (plain, for row addressing)
  const int p0 = blockIdx.x * 128;
  int ob = wv * 16;                // wave's 16-output base (scalar weights)
  ob = __builtin_amdgcn_readfirstlane(ob);
  const int px0 = lane, px1 = lane + 64;
  if (t < 16) lh[t] = 0;
  // stage W3 (read only in phase 3; own buffer, no hazard)
  for (int i = t; i < 17 * 128; i += 512)
    w3s[(i & 127) * 20 + (i >> 7)] = W3[i];

  const float* __restrict__ W1u = WT1 + ob;
  const float* __restrict__ W2u = WT2 + ob;
  float acc1[32];                  // [o][p]: acc1[2o+p]
#pragma unroll
  for (int o = 0; o < 16; ++o) {
    const float b = Bv1[ob + o];
    acc1[2 * o] = b; acc1[2 * o + 1] = b;
  }

  // ---- stage raw x half 0 (k rows 0..63; wave stages rows wv*8..+8) ----
  {
    const int rb = wv * 8;
    float xr[16];
#pragma unroll
    for (int j = 0; j < 8; ++j) {
      xr[2 * j]     = X[(rb + j) * NPIX + p0 + px0];
      xr[2 * j + 1] = X[(rb + j) * NPIX + p0 + px1];
    }
#pragma unroll
    for (int j = 0; j < 8; ++j) {
      xbuf[rb + j][px0] = xr[2 * j];
      xbuf[rb + j][px1] = xr[2 * j + 1];
    }
  }
  __syncthreads();

  // ---- phase 1a: conv1 k=0..63 ----
#pragma unroll 4
  for (int k = 0; k < 64; ++k) {
    const float xa = xbuf[k][px0];
    const float xb = xbuf[k][px1];
#pragma unroll
    for (int o = 0; o < 16; ++o) {
      const float wgt = W1u[k * 128 + o];
      acc1[2 * o]     = fmaf(xa, wgt, acc1[2 * o]);
      acc1[2 * o + 1] = fmaf(xb, wgt, acc1[2 * o + 1]);
    }
  }
  // transpose half 0: xt cols 0..63 (coalesced 4-thread 256B bursts)
#pragma unroll
  for (int i = 0; i < 4; ++i) {
    const int idx = t * 4 + i;
    const int tok = idx >> 4, c4 = idx & 15;
    const int pg = p0 + tok;
    float4 v;
    v.x = xbuf[c4 * 4 + 0][tok];
    v.y = xbuf[c4 * 4 + 1][tok];
    v.z = xbuf[c4 * 4 + 2][tok];
    v.w = xbuf[c4 * 4 + 3][tok];
    *(float4*)(xt + ((pg & 255) * H_ + (pg >> 8)) * 128 + c4 * 4) = v;
  }
  __syncthreads();

  // ---- stage raw x half 1 (k rows 64..127) ----
  {
    const int rb = wv * 8;
    float xr[16];
#pragma unroll
    for (int j = 0; j < 8; ++j) {
      xr[2 * j]     = X[(64 + rb + j) * NPIX + p0 + px0];
      xr[2 * j + 1] = X[(64 + rb + j) * NPIX + p0 + px1];
    }
#pragma unroll
    for (int j = 0; j < 8; ++j) {
      xbuf[rb + j][px0] = xr[2 * j];
      xbuf[rb + j][px1] = xr[2 * j + 1];
    }
  }
  __syncthreads();

  // ---- phase 1b: conv1 k=64..127 ----
#pragma unroll 4
  for (int k = 64; k < 128; ++k) {
    const float xa = xbuf[k - 64][px0];
    const float xb = xbuf[k - 64][px1];
#pragma unroll
    for (int o = 0; o < 16; ++o) {
      const float wgt = W1u[k * 128 + o];
      acc1[2 * o]     = fmaf(xa, wgt, acc1[2 * o]);
      acc1[2 * o + 1] = fmaf(xb, wgt, acc1[2 * o + 1]);
    }
  }
  // transpose half 1: xt cols 64..127
#pragma unroll
  for (int i = 0; i < 4; ++i) {
    const int idx = t * 4 + i;
    const int tok = idx >> 4, c4 = idx & 15;
    const int pg = p0 + tok;
    float4 v;
    v.x = xbuf[c4 * 4 + 0][tok];
    v.y = xbuf[c4 * 4 + 1][tok];
    v.z = xbuf[c4 * 4 + 2][tok];
    v.w = xbuf[c4 * 4 + 3][tok];
    *(float4*)(xt + ((pg & 255) * H_ + (pg >> 8)) * 128 + 64 + c4 * 4) = v;
  }
  __syncthreads();

  // ---- epilogue 1a: waves 0-3 write lrelu(conv1) channels 0..63 ----
  if (wv < 4) {
    const int rb = wv * 16;
#pragma unroll
    for (int o = 0; o < 16; ++o) {
      float va = acc1[2 * o], vb = acc1[2 * o + 1];
      va = va > 0.f ? va : 0.01f * va;
      vb = vb > 0.f ? vb : 0.01f * vb;
      xbuf[rb + o][px0] = va;
      xbuf[rb + o][px1] = vb;
    }
  }
  __syncthreads();

  // ---- phase 2a: conv2 k=0..63 ----
  float acc2[32];
#pragma unroll
  for (int o = 0; o < 16; ++o) {
    const float b = Bv2[ob + o];
    acc2[2 * o] = b; acc2[2 * o + 1] = b;
  }
#pragma unroll 4
  for (int k = 0; k < 64; ++k) {
    const float xa = xbuf[k][px0];
    const float xb = xbuf[k][px1];
#pragma unroll
    for (int o = 0; o < 16; ++o) {
      const float wgt = W2u[k * 128 + o];
      acc2[2 * o]     = fmaf(xa, wgt, acc2[2 * o]);
      acc2[2 * o + 1] = fmaf(xb, wgt, acc2[2 * o + 1]);
    }
  }
  __syncthreads();

  // ---- epilogue 1b: waves 4-7 write lrelu(conv1) channels 64..127 ----
  if (wv >= 4) {
    const int rb = (wv - 4) * 16;
#pragma unroll
    for (int o = 0; o < 16; ++o) {
      float va = acc1[2 * o], vb = acc1[2 * o + 1];
      va = va > 0.f ? va : 0.01f * va;
      vb = vb > 0.f ? vb : 0.01f * vb;
      xbuf[rb + o][px0] = va;
      xbuf[rb + o][px1] = vb;
    }
  }
  __syncthreads();

  // ---- phase 2b: conv2 k=64..127 ----
#pragma unroll 4
  for (int k = 64; k < 128; ++k) {
    const float xa = xbuf[k - 64][px0];
    const float xb = xbuf[k - 64][px1];
#pragma unroll
    for (int o = 0; o < 16; ++o) {
      const float wgt = W2u[k * 128 + o];
      acc2[2 * o]     = fmaf(xa, wgt, acc2[2 * o]);
      acc2[2 * o + 1] = fmaf(xb, wgt, acc2[2 * o + 1]);
    }
  }
  __syncthreads();

  // ---- epilogue 2a: waves 0-3 write lrelu(conv2) channels 0..63 ----
  if (wv < 4) {
    const int rb = wv * 16;
#pragma unroll
    for (int o = 0; o < 16; ++o) {
      float va = acc2[2 * o], vb = acc2[2 * o + 1];
      va = va > 0.f ? va : 0.01f * va;
      vb = vb > 0.f ? vb : 0.01f * vb;
      xbuf[rb + o][px0] = va;
      xbuf[rb + o][px1] = vb;
    }
  }
  __syncthreads();

  // ---- phase 3a: conv17 partial k=0..63 (4 lanes per pixel) ----
  const int p = t >> 2, s = t & 3;    // pixel 0..127, logit-quad owner
  float s4[4];
#pragma unroll
  for (int j = 0; j < 4; ++j) s4[j] = Bv3[s * 4 + j];
  float m = Bv3[16];
#pragma unroll 8
  for (int k = 0; k < 64; ++k) {
    const float xv = xbuf[k][p];
    float w4[4];
    *(float4*)w4 = *(const float4*)&w3s[k * 20 + s * 4];
#pragma unroll
    for (int j = 0; j < 4; ++j) s4[j] = fmaf(xv, w4[j], s4[j]);
    m = fmaf(xv, w3s[k * 20 + 16], m);
  }
  __syncthreads();

  // ---- epilogue 2b: waves 4-7 write lrelu(conv2) channels 64..127 ----
  if (wv >= 4) {
    const int rb = (wv - 4) * 16;
#pragma unroll
    for (int o = 0; o < 16; ++o) {
      float va = acc2[2 * o], vb = acc2[2 * o + 1];
      va = va > 0.f ? va : 0.01f * va;
      vb = vb > 0.f ? vb : 0.01f * vb;
      xbuf[rb + o][px0] = va;
      xbuf[rb + o][px1] = vb;
    }
  }
  __syncthreads();

  // ---- phase 3b: conv17 k=64..127 + argmax + mask + hist ----
#pragma unroll 8
  for (int k = 64; k < 128; ++k) {
    const float xv = xbuf[k - 64][p];
    float w4[4];
    *(float4*)w4 = *(const float4*)&w3s[k * 20 + s * 4];
#pragma unroll
    for (int j = 0; j < 4; ++j) s4[j] = fmaf(xv, w4[j], s4[j]);
    m = fmaf(xv, w3s[k * 20 + 16], m);
  }
  {
    // argmax over 16: local first-max-wins over quad, then min-index-of-max
    float bv = s4[0];
    int bi = s * 4;
#pragma unroll
    for (int j = 1; j < 4; ++j) {
      if (s4[j] > bv) { bv = s4[j]; bi = s * 4 + j; }
    }
#pragma unroll
    for (int d = 1; d < 4; d <<= 1) {
      const float ov = __shfl_xor(bv, d, 64);
      const int oi = __shfl_xor(bi, d, 64);
      if (ov > bv || (ov == bv && oi < bi)) { bv = ov; bi = oi; }
    }
    if (s == 0) {
      inds1[p0 + p] = (unsigned char)bi;
      mask_out[p0 + p] = m > 0.f ? m : 0.01f * m;
      atomicAdd(&lh[bi], 1);
    }
  }
  __syncthreads();
  if (t < 16 && lh[t] > 0) atomicAdd(&cnt1[t], lh[t]);
}

// ---------------------------------------------------------------------------
// two-level scatter; bin offsets computed in-block from cnt (shfl scan)
// ---------------------------------------------------------------------------
template<typename T>
__global__ __launch_bounds__(256) void scatter_k(const T* __restrict__ bins,
    const int* __restrict__ cnt, int* __restrict__ cursor,
    int* __restrict__ ord, int nbins) {
  __shared__ int loff[256], lhist[256], lbase[256], lcur[256];
  __shared__ int wsC[4];
  const int t = threadIdx.x;
  const int lane = t & 63, wvi = t >> 6;
  const int c = (t < nbins) ? cnt[t] : 0;
  int ic = c;
  for (int d = 1; d < 64; d <<= 1) {
    const int u = __shfl_up(ic, d, 64);
    if (lane >= d) ic += u;
  }
  if (lane == 63) wsC[wvi] = ic;
  if (t < nbins) { lhist[t] = 0; lcur[t] = 0; }
  __syncthreads();
  int bc = 0;
#pragma unroll
  for (int w2 = 0; w2 < 4; ++w2) if (w2 < wvi) bc += wsC[w2];
  ic += bc;
  if (t < nbins) loff[t] = ic - c;
  __syncthreads();
  const int n = blockIdx.x * 256 + t;
  const int b = (int)bins[n];
  atomicAdd(&lhist[b], 1);
  __syncthreads();
  if (t < nbins && lhist[t] > 0) lbase[t] = atomicAdd(&cursor[t], lhist[t]);
  __syncthreads();
  const int r = atomicAdd(&lcur[b], 1);
  ord[loff[b] + lbase[b] + r] = n;
}

// ---------------------------------------------------------------------------
// chain1 v5: LDS-staged expert weights + x rows; pure-LDS k-loop.
// Descriptor (e, chunk, off, cnt) derived in-block from cnt1 via shfl scan.
// ---------------------------------------------------------------------------
__global__ __launch_bounds__(256) void chain1_k(const float* __restrict__ xt,
    const int* __restrict__ ord1, const int* __restrict__ cnt1,
    const float* __restrict__ wc21, const float* __restrict__ bc21,
    const float* __restrict__ wc22, const float* __restrict__ bc22,
    const float* __restrict__ wc23, const float* __restrict__ bc23,
    int* __restrict__ e12a, int* __restrict__ cnt2) {
  __shared__ float w1s[4096];
  __shared__ float w2s[1024];
  __shared__ float w3s[512];
  __shared__ float bs[80];
  __shared__ float xs_[64][132];
  __shared__ int lh[16];
  __shared__ int sel[4];
  __shared__ int wsC[4], wsD[4];
  const int t = threadIdx.x;
  const int lane = t & 63, wvi = t >> 6;
  if (t == 0) sel[0] = -1;
  if (t < 16) lh[t] = 0;
  {
    const int cb = (t < 16) ? cnt1[t] : 0;
    const int nb = (cb + TPB - 1) / TPB;
    int ic = cb, id = nb;
    for (int d = 1; d < 64; d <<= 1) {
      const int uc = __shfl_up(ic, d, 64);
      const int ud = __shfl_up(id, d, 64);
      if (lane >= d) { ic += uc; id += ud; }
    }
    if (lane == 63) { wsC[wvi] = ic; wsD[wvi] = id; }
    __syncthreads();
    int bc = 0, bd = 0;
#pragma unroll
    for (int w2 = 0; w2 < 4; ++w2) {
      if (w2 < wvi) { bc += wsC[w2]; bd += wsD[w2]; }
    }
    ic += bc; id += bd;
    const int accB = id - nb, accO = ic - cb;
    if (t < 16 && (int)blockIdx.x >= accB && (int)blockIdx.x < accB + nb) {
      sel[0] = t; sel[1] = blockIdx.x - accB; sel[2] = accO; sel[3] = cb;
    }
  }
  __syncthreads();
  if (sel[0] < 0) return;
  const int e     = __builtin_amdgcn_readfirstlane(sel[0]);
  const int chunk = __builtin_amdgcn_readfirstlane(sel[1]);
  const int offe  = __builtin_amdgcn_readfirstlane(sel[2]);
  const int cnt   = __builtin_amdgcn_readfirstlane(sel[3]);

  const int tg = t >> 2, sub = t & 3;
  const int l0 = (t & 63) & ~3;
  const int pos = chunk * TPB + tg;
  const bool valid = pos < cnt;
  const int n = valid ? ord1[offe + pos] : 0;

  {
    const float4* __restrict__ Wg1 = (const float4*)(wc21 + e * 4096);
#pragma unroll
    for (int j = 0; j < 4; ++j)
      *(float4*)&w1s[t * 4 + j * 1024] = Wg1[t + j * 256];
    const float4* __restrict__ Wg2 = (const float4*)(wc22 + e * 1024);
    *(float4*)&w2s[t * 4] = Wg2[t];
    if (t < 128) {
      const float4* __restrict__ Wg3 = (const float4*)(wc23 + e * 512);
      *(float4*)&w3s[t * 4] = Wg3[t];
    }
    if (t < 32) bs[t] = bc21[e * 32 + t];
    else if (t < 64) bs[t] = bc22[e * 32 + (t - 32)];
    else if (t < 80) bs[t] = bc23[e * 16 + (t - 64)];
  }
  {
    const float4* __restrict__ src = (const float4*)(xt + n * 128 + sub * 32);
    float4 tmp[8];
#pragma unroll
    for (int j = 0; j < 8; ++j) tmp[j] = src[j];
#pragma unroll
    for (int j = 0; j < 8; ++j)
      *(float4*)(&xs_[tg][sub * 32 + 4 * j]) = tmp[j];
  }
  __syncthreads();

  const int wb1 = sub * 8;
  float a[8];
#pragma unroll
  for (int o = 0; o < 8; ++o) a[o] = bs[wb1 + o];
#pragma unroll
  for (int k = 0; k < 128; k += 4) {
    float x4[4];
    *(float4*)x4 = *(const float4*)(&xs_[tg][k]);
#pragma unroll
    for (int kk = 0; kk < 4; ++kk) {
      float w8[8];
      *(float4*)&w8[0] = *(const float4*)&w1s[(k + kk) * 32 + wb1];
      *(float4*)&w8[4] = *(const float4*)&w1s[(k + kk) * 32 + wb1 + 4];
#pragma unroll
      for (int o = 0; o < 8; ++o) a[o] = fmaf(x4[kk], w8[o], a[o]);
    }
  }
#pragma unroll
  for (int o = 0; o < 8; ++o) a[o] = a[o] > 0.f ? a[o] : 0.01f * a[o];

  float b[8];
#pragma unroll
  for (int o = 0; o < 8; ++o) b[o] = bs[32 + wb1 + o];
#pragma unroll
  for (int i = 0; i < 32; ++i) {
    const float hv = __shfl(a[i & 7], l0 + (i >> 3), 64);
    float w8[8];
    *(float4*)&w8[0] = *(const float4*)&w2s[i * 32 + wb1];
    *(float4*)&w8[4] = *(const float4*)&w2s[i * 32 + wb1 + 4];
#pragma unroll
    for (int o = 0; o < 8; ++o) b[o] = fmaf(hv, w8[o], b[o]);
  }
#pragma unroll
  for (int o = 0; o < 8; ++o) b[o] = b[o] > 0.f ? b[o] : 0.01f * b[o];

  float s[4];
#pragma unroll
  for (int j = 0; j < 4; ++j) s[j] = bs[64 + sub * 4 + j];
#pragma unroll
  for (int i = 0; i < 32; ++i) {
    const float hv = __shfl(b[i & 7], l0 + (i >> 3), 64);
    float w4[4];
    *(float4*)w4 = *(const float4*)&w3s[i * 16 + sub * 4];
#pragma unroll
    for (int j = 0; j < 4; ++j) s[j] = fmaf(hv, w4[j], s[j]);
  }

  float bv = s[0];
  int bi = sub * 4;
#pragma unroll
  for (int j = 1; j < 4; ++j) {
    if (s[j] > bv) { bv = s[j]; bi = sub * 4 + j; }
  }
#pragma unroll
  for (int d = 1; d < 4; d <<= 1) {
    const float ov = __shfl_xor(bv, d, 64);
    const int oi = __shfl_xor(bi, d, 64);
    if (ov > bv || (ov == bv && oi < bi)) { bv = ov; bi = oi; }
  }
  const int e12 = e * 16 + bi;
  if (valid && sub == 0) {
    e12a[n] = e12;
    atomicAdd(&lh[bi], 1);
  }
  __syncthreads();
  if (t < 16 && lh[t] > 0)
    atomicAdd(&cnt2[e * 16 + t], lh[t]);
}

// ---------------------------------------------------------------------------
// chain2 v5: LDS-weight-staged; descriptor from cnt2 (256 bins).
// ---------------------------------------------------------------------------
__global__ __launch_bounds__(256) void chain2_k(const float* __restrict__ xt,
    const int* __restrict__ ord2, const int* __restrict__ cnt2,
    const float* __restrict__ wr11, const float* __restrict__ br11,
    const float* __restrict__ wr12, const float* __restrict__ br12,
    const float* __restrict__ wr13, const float* __restrict__ br13,
    float* __restrict__ out) {
  __shared__ float w1s[4096];
  __shared__ float w2s[512];
  __shared__ float w3s[16];
  __shared__ float bs[49];
  __shared__ float xs_[64][132];
  __shared__ int sel[4];
  __shared__ int wsC[4], wsD[4];
  const int t = threadIdx.x;
  const int lane = t & 63, wvi = t >> 6;
  if (t == 0) sel[0] = -1;
  {
    const int cb = cnt2[t];
    const int nb = (cb + TPB - 1) / TPB;
    int ic = cb, id = nb;
    for (int d = 1; d < 64; d <<= 1) {
      const int uc = __shfl_up(ic, d, 64);
      const int ud = __shfl_up(id, d, 64);
      if (lane >= d) { ic += uc; id += ud; }
    }
    if (lane == 63) { wsC[wvi] = ic; wsD[wvi] = id; }
    __syncthreads();
    int bc = 0, bd = 0;
#pragma unroll
    for (int w2 = 0; w2 < 4; ++w2) {
      if (w2 < wvi) { bc += wsC[w2]; bd += wsD[w2]; }
    }
    ic += bc; id += bd;
    const int accB = id - nb, accO = ic - cb;
    if ((int)blockIdx.x >= accB && (int)blockIdx.x < accB + nb) {
      sel[0] = t; sel[1] = blockIdx.x - accB; sel[2] = accO; sel[3] = cb;
    }
  }
  __syncthreads();
  if (sel[0] < 0) return;
  const int e12   = __builtin_amdgcn_readfirstlane(sel[0]);
  const int chunk = __builtin_amdgcn_readfirstlane(sel[1]);
  const int offe  = __builtin_amdgcn_readfirstlane(sel[2]);
  const int cnt   = __builtin_amdgcn_readfirstlane(sel[3]);

  const int tg = t >> 2, sub = t & 3;
  const int l0 = (t & 63) & ~3;
  const int pos = chunk * TPB + tg;
  const bool valid = pos < cnt;
  const int n = valid ? ord2[offe + pos] : 0;

  {
    const float4* __restrict__ Wg1 = (const float4*)(wr11 + e12 * 4096);
#pragma unroll
    for (int j = 0; j < 4; ++j)
      *(float4*)&w1s[t * 4 + j * 1024] = Wg1[t + j * 256];
    if (t < 128) {
      const float4* __restrict__ Wg2 = (const float4*)(wr12 + e12 * 512);
      *(float4*)&w2s[t * 4] = Wg2[t];
    }
    if (t < 16) w3s[t] = wr13[e12 * 16 + t];
    if (t < 32) bs[t] = br11[e12 * 32 + t];
    else if (t < 48) bs[t] = br12[e12 * 16 + (t - 32)];
    else if (t == 48) bs[48] = br13[e12];
  }
  {
    const float4* __restrict__ src = (const float4*)(xt + n * 128 + sub * 32);
    float4 tmp[8];
#pragma unroll
    for (int j = 0; j < 8; ++j) tmp[j] = src[j];
#pragma unroll
    for (int j = 0; j < 8; ++j)
      *(float4*)(&xs_[tg][sub * 32 + 4 * j]) = tmp[j];
  }
  __syncthreads();

  const int wb1 = sub * 8;
  float a[8];
#pragma unroll
  for (int o = 0; o < 8; ++o) a[o] = bs[wb1 + o];
#pragma unroll
  for (int k = 0; k < 128; k += 4) {
    float x4[4];
    *(float4*)x4 = *(const float4*)(&xs_[tg][k]);
#pragma unroll
    for (int kk = 0; kk < 4; ++kk) {
      float w8[8];
      *(float4*)&w8[0] = *(const float4*)&w1s[(k + kk) * 32 + wb1];
      *(float4*)&w8[4] = *(const float4*)&w1s[(k + kk) * 32 + wb1 + 4];
#pragma unroll
      for (int o = 0; o < 8; ++o) a[o] = fmaf(x4[kk], w8[o], a[o]);
    }
  }
#pragma unroll
  for (int o = 0; o < 8; ++o) a[o] = a[o] > 0.f ? a[o] : 0.01f * a[o];

  float s[4];
#pragma unroll
  for (int j = 0; j < 4; ++j) s[j] = bs[32 + sub * 4 + j];
#pragma unroll
  for (int i = 0; i < 32; ++i) {
    const float hv = __shfl(a[i & 7], l0 + (i >> 3), 64);
    float w4[4];
    *(float4*)w4 = *(const float4*)&w2s[i * 16 + sub * 4];
#pragma unroll
    for (int j = 0; j < 4; ++j) s[j] = fmaf(hv, w4[j], s[j]);
  }
#pragma unroll
  for (int j = 0; j < 4; ++j) s[j] = s[j] > 0.f ? s[j] : 0.01f * s[j];

  float r = bs[48];
#pragma unroll
  for (int i = 0; i < 16; ++i) {
    const float hv = __shfl(s[i & 3], l0 + (i >> 2), 64);
    r = fmaf(hv, w3s[i], r);
  }

  if (valid && sub == 0) out[n] = ((float)e12 + r) * (1.0f / 256.0f);
}

// ---------------------------------------------------------------------------
extern "C" void kernel_launch(void* const* d_in, const int* in_sizes, int n_in,
                              void* d_out, int out_size, void* d_ws,
                              size_t ws_size, hipStream_t stream) {
  const float* x_in  = (const float*)d_in[0];
  const float* w_c11 = (const float*)d_in[1];
  const float* b_c11 = (const float*)d_in[2];
  const float* w_c12 = (const float*)d_in[3];
  const float* b_c12 = (const float*)d_in[4];
  const float* w_c13 = (const float*)d_in[5];
  const float* b_c13 = (const float*)d_in[6];
  const float* w_c21 = (const float*)d_in[7];
  const float* b_c21 = (const float*)d_in[8];
  const float* w_c22 = (const float*)d_in[9];
  const float* b_c22 = (const float*)d_in[10];
  const float* w_c23 = (const float*)d_in[11];
  const float* b_c23 = (const float*)d_in[12];
  const float* w_r11 = (const float*)d_in[13];
  const float* b_r11 = (const float*)d_in[14];
  const float* w_r12 = (const float*)d_in[15];
  const float* b_r12 = (const float*)d_in[16];
  const float* w_r13 = (const float*)d_in[17];
  const float* b_r13 = (const float*)d_in[18];

  float* out = (float*)d_out;   // [0..N): x_real (token order), [N..2N): mask

  float* R0 = (float*)d_ws;
  float* R1 = R0 + 128 * NPIX;
  float* R2 = R1 + 128 * NPIX;

  float* xt = R0;
  unsigned char* inds1 = (unsigned char*)R2;   // N bytes
  float* wT1 = R2 + 12288;
  float* wT2 = wT1 + 16384;
  int* S = (int*)R2 + 45056;

  int* cnt1 = S;             // 16
  int* cur1 = S + 16;        // 16
  int* cnt2 = S + 1088;      // 256
  int* cur2 = S + 1344;      // 256

  int* ib   = (int*)R1;
  int* ord1 = ib;            // N
  int* ord2 = ib + NPIX;     // N
  int* e12a = ib + 2 * NPIX; // N

  wtrans2_k<<<32, 256, 0, stream>>>(w_c11, wT1, w_c12, wT2, S);
  convfused_k<<<NPIX / 128, 512, 0, stream>>>(x_in, wT1, b_c11, wT2, b_c12,
      w_c13, b_c13, inds1, out + NPIX, cnt1, xt);
  scatter_k<unsigned char><<<NPIX / 256, 256, 0, stream>>>(inds1, cnt1, cur1,
                                                           ord1, 16);
  chain1_k<<<NPIX / TPB + 16, 256, 0, stream>>>(xt, ord1, cnt1,
      w_c21, b_c21, w_c22, b_c22, w_c23, b_c23, e12a, cnt2);
  scatter_k<int><<<NPIX / 256, 256, 0, stream>>>(e12a, cnt2, cur2, ord2, 256);
  chain2_k<<<NPIX / TPB + 256, 256, 0, stream>>>(xt, ord2, cnt2,
      w_r11, b_r11, w_r12, b_r12, w_r13, b_r13, out);
}

// Round 21
// 115.346 us; speedup vs baseline: 1.0688x; 1.0688x over previous
//
#include <hip/hip_runtime.h>

#define NPIX 49152   // B*H*W = 1*192*256
#define H_ 192
#define W_ 256
#define TPB 64       // tokens per chain block (64 tokens; 256 thr = 4 waves)

// ---------------------------------------------------------------------------
// both weight transposes (32 blocks) + zero binning counters (block 0)
// ---------------------------------------------------------------------------
__global__ __launch_bounds__(256) void wtrans2_k(const float* __restrict__ Wa,
    float* __restrict__ WTa, const float* __restrict__ Wb,
    float* __restrict__ WTb, int* __restrict__ S) {
  const int b = blockIdx.x;
  const float* __restrict__ W = (b < 16) ? Wa : Wb;
  float* __restrict__ WT = (b < 16) ? WTa : WTb;
  const int bb = b & 15;
  __shared__ float tile[32][33];
  const int bx = bb & 3, by = bb >> 2;
  const int c = threadIdx.x & 31, r0 = threadIdx.x >> 5;
#pragma unroll
  for (int j = 0; j < 4; ++j) {
    const int r = r0 + j * 8;
    tile[r][c] = W[(by * 32 + r) * 128 + bx * 32 + c];
  }
  __syncthreads();
#pragma unroll
  for (int j = 0; j < 4; ++j) {
    const int r = r0 + j * 8;
    WT[(bx * 32 + r) * 128 + by * 32 + c] = tile[c][r];
  }
  if (b == 0) {
    const int t = threadIdx.x;
    if (t < 32) S[t] = 0;        // cnt1 + cur1
    S[1088 + t] = 0;             // cnt2
    S[1344 + t] = 0;             // cur2
  }
}

// ---------------------------------------------------------------------------
// FUSED conv1 + conv2 + conv17 + argmax + mask + histogram + x transpose.
// (round-13/16 version, proven ~58 µs: 512 thr, 16 outputs/wave, scalar
//  weights — the s_load path pays because all blocks share the matrices)
// ---------------------------------------------------------------------------
__global__ __launch_bounds__(512) void convfused_k(const float* __restrict__ X,
    const float* __restrict__ WT1, const float* __restrict__ Bv1,
    const float* __restrict__ WT2, const float* __restrict__ Bv2,
    const float* __restrict__ W3, const float* __restrict__ Bv3,
    unsigned char* __restrict__ inds1, float* __restrict__ mask_out,
    int* __restrict__ cnt1, float* __restrict__ xt) {
  __shared__ float xs2[128][65];   // 33.3 KB raw x, then activations (pad 65)
  __shared__ float w3s[128 * 20];  // 10 KB W3 [k][20]
  __shared__ int lh[16];
  const int t = threadIdx.x;
  const int px = t & 63;           // lane = pixel within tile
  const int p0 = blockIdx.x * 64;
  int ob = (t >> 6) * 16;          // wave's 16-output base == its k-row base
  ob = __builtin_amdgcn_readfirstlane(ob);
  if (t < 16) lh[t] = 0;

  // ---- stage raw x: wave w loads k rows [ob, ob+16) for all 64 px ----
  {
    float xr[16];
#pragma unroll
    for (int kk = 0; kk < 16; ++kk)
      xr[kk] = X[(ob + kk) * NPIX + p0 + px];
#pragma unroll
    for (int kk = 0; kk < 16; ++kk)
      xs2[ob + kk][px] = xr[kk];
  }
  __syncthreads();

  float acc[16];

  // ================= PHASE 1: conv1 (x from LDS, W scalar) ===============
  const float* __restrict__ W1u = WT1 + ob;   // uniform base
#pragma unroll
  for (int o = 0; o < 16; ++o) acc[o] = Bv1[ob + o];
#pragma unroll 8
  for (int k = 0; k < 128; ++k) {
    const float xv = xs2[k][px];
#pragma unroll
    for (int o = 0; o < 16; ++o)
      acc[o] = fmaf(xv, W1u[k * 128 + o], acc[o]);
  }

  // ---- xt transpose write (coalesced row bursts from LDS cols) ----
#pragma unroll
  for (int i = 0; i < 4; ++i) {
    const int idx = t * 4 + i;
    const int tok = idx >> 5, c4 = idx & 31;   // token 0..63, f4-col 0..31
    const int pg = p0 + tok;
    float4 v;
    v.x = xs2[c4 * 4 + 0][tok];
    v.y = xs2[c4 * 4 + 1][tok];
    v.z = xs2[c4 * 4 + 2][tok];
    v.w = xs2[c4 * 4 + 3][tok];
    *(float4*)(xt + ((pg & 255) * H_ + (pg >> 8)) * 128 + c4 * 4) = v;
  }
  __syncthreads();   // xt LDS reads + phase-1 reads done before overwrite

  // epilogue 1: lrelu -> xs2 (activations)
#pragma unroll
  for (int o = 0; o < 16; ++o) {
    const float v = acc[o];
    xs2[ob + o][px] = v > 0.f ? v : 0.01f * v;
  }
  __syncthreads();

  // ================= PHASE 2: conv2 (x from LDS, W scalar) ===============
  const float* __restrict__ W2u = WT2 + ob;
#pragma unroll
  for (int o = 0; o < 16; ++o) acc[o] = Bv2[ob + o];
#pragma unroll 8
  for (int k = 0; k < 128; ++k) {
    const float xv = xs2[k][px];
#pragma unroll
    for (int o = 0; o < 16; ++o)
      acc[o] = fmaf(xv, W2u[k * 128 + o], acc[o]);
  }
  __syncthreads();   // all phase-2 reads of xs2 complete

  // epilogue 2: lrelu -> xs2 ; stage W3 as w3s[k][20]
#pragma unroll
  for (int o = 0; o < 16; ++o) {
    const float v = acc[o];
    xs2[ob + o][px] = v > 0.f ? v : 0.01f * v;
  }
  for (int i = t; i < 17 * 128; i += 512)
    w3s[(i & 127) * 20 + (i >> 7)] = W3[i];
  __syncthreads();

  // ===== PHASE 3: conv17 + argmax + mask + hist (8 lanes per pixel) =====
  {
    const int p = t >> 3, s = t & 7;      // pixel 0..63, logit-pair owner
    float s2[2];
    s2[0] = Bv3[2 * s];
    s2[1] = Bv3[2 * s + 1];
    float m = Bv3[16];
#pragma unroll 8
    for (int k = 0; k < 128; ++k) {
      const float xv = xs2[k][p];
      float2 w2 = *(const float2*)&w3s[k * 20 + 2 * s];
      s2[0] = fmaf(xv, w2.x, s2[0]);
      s2[1] = fmaf(xv, w2.y, s2[1]);
      m = fmaf(xv, w3s[k * 20 + 16], m);
    }
    float bv = s2[0];
    int bi = 2 * s;
    if (s2[1] > bv) { bv = s2[1]; bi = 2 * s + 1; }
#pragma unroll
    for (int d = 1; d < 8; d <<= 1) {
      const float ov = __shfl_xor(bv, d, 64);
      const int oi = __shfl_xor(bi, d, 64);
      if (ov > bv || (ov == bv && oi < bi)) { bv = ov; bi = oi; }
    }
    if (s == 0) {
      inds1[p0 + p] = (unsigned char)bi;
      mask_out[p0 + p] = m > 0.f ? m : 0.01f * m;
      atomicAdd(&lh[bi], 1);
    }
  }
  __syncthreads();
  if (t < 16 && lh[t] > 0) atomicAdd(&cnt1[t], lh[t]);
}

// ---------------------------------------------------------------------------
// two-level scatter; bin offsets computed in-block from cnt (shfl scan)
// ---------------------------------------------------------------------------
template<typename T>
__global__ __launch_bounds__(256) void scatter_k(const T* __restrict__ bins,
    const int* __restrict__ cnt, int* __restrict__ cursor,
    int* __restrict__ ord, int nbins) {
  __shared__ int loff[256], lhist[256], lbase[256], lcur[256];
  __shared__ int wsC[4];
  const int t = threadIdx.x;
  const int lane = t & 63, wvi = t >> 6;
  const int c = (t < nbins) ? cnt[t] : 0;
  int ic = c;
  for (int d = 1; d < 64; d <<= 1) {
    const int u = __shfl_up(ic, d, 64);
    if (lane >= d) ic += u;
  }
  if (lane == 63) wsC[wvi] = ic;
  if (t < nbins) { lhist[t] = 0; lcur[t] = 0; }
  __syncthreads();
  int bc = 0;
#pragma unroll
  for (int w2 = 0; w2 < 4; ++w2) if (w2 < wvi) bc += wsC[w2];
  ic += bc;
  if (t < nbins) loff[t] = ic - c;
  __syncthreads();
  const int n = blockIdx.x * 256 + t;
  const int b = (int)bins[n];
  atomicAdd(&lhist[b], 1);
  __syncthreads();
  if (t < nbins && lhist[t] > 0) lbase[t] = atomicAdd(&cursor[t], lhist[t]);
  __syncthreads();
  const int r = atomicAdd(&lcur[b], 1);
  ord[loff[b] + lbase[b] + r] = n;
}

// ---------------------------------------------------------------------------
// chain1 v5: LDS-staged expert weights + x rows; pure-LDS k-loop.
// Descriptor (e, chunk, off, cnt) derived in-block from cnt1 via shfl scan.
// ---------------------------------------------------------------------------
__global__ __launch_bounds__(256) void chain1_k(const float* __restrict__ xt,
    const int* __restrict__ ord1, const int* __restrict__ cnt1,
    const float* __restrict__ wc21, const float* __restrict__ bc21,
    const float* __restrict__ wc22, const float* __restrict__ bc22,
    const float* __restrict__ wc23, const float* __restrict__ bc23,
    int* __restrict__ e12a, int* __restrict__ cnt2) {
  __shared__ float w1s[4096];
  __shared__ float w2s[1024];
  __shared__ float w3s[512];
  __shared__ float bs[80];
  __shared__ float xs_[64][132];
  __shared__ int lh[16];
  __shared__ int sel[4];
  __shared__ int wsC[4], wsD[4];
  const int t = threadIdx.x;
  const int lane = t & 63, wvi = t >> 6;
  if (t == 0) sel[0] = -1;
  if (t < 16) lh[t] = 0;
  {
    const int cb = (t < 16) ? cnt1[t] : 0;
    const int nb = (cb + TPB - 1) / TPB;
    int ic = cb, id = nb;
    for (int d = 1; d < 64; d <<= 1) {
      const int uc = __shfl_up(ic, d, 64);
      const int ud = __shfl_up(id, d, 64);
      if (lane >= d) { ic += uc; id += ud; }
    }
    if (lane == 63) { wsC[wvi] = ic; wsD[wvi] = id; }
    __syncthreads();
    int bc = 0, bd = 0;
#pragma unroll
    for (int w2 = 0; w2 < 4; ++w2) {
      if (w2 < wvi) { bc += wsC[w2]; bd += wsD[w2]; }
    }
    ic += bc; id += bd;
    const int accB = id - nb, accO = ic - cb;
    if (t < 16 && (int)blockIdx.x >= accB && (int)blockIdx.x < accB + nb) {
      sel[0] = t; sel[1] = blockIdx.x - accB; sel[2] = accO; sel[3] = cb;
    }
  }
  __syncthreads();
  if (sel[0] < 0) return;
  const int e     = __builtin_amdgcn_readfirstlane(sel[0]);
  const int chunk = __builtin_amdgcn_readfirstlane(sel[1]);
  const int offe  = __builtin_amdgcn_readfirstlane(sel[2]);
  const int cnt   = __builtin_amdgcn_readfirstlane(sel[3]);

  const int tg = t >> 2, sub = t & 3;
  const int l0 = (t & 63) & ~3;
  const int pos = chunk * TPB + tg;
  const bool valid = pos < cnt;
  const int n = valid ? ord1[offe + pos] : 0;

  {
    const float4* __restrict__ Wg1 = (const float4*)(wc21 + e * 4096);
#pragma unroll
    for (int j = 0; j < 4; ++j)
      *(float4*)&w1s[t * 4 + j * 1024] = Wg1[t + j * 256];
    const float4* __restrict__ Wg2 = (const float4*)(wc22 + e * 1024);
    *(float4*)&w2s[t * 4] = Wg2[t];
    if (t < 128) {
      const float4* __restrict__ Wg3 = (const float4*)(wc23 + e * 512);
      *(float4*)&w3s[t * 4] = Wg3[t];
    }
    if (t < 32) bs[t] = bc21[e * 32 + t];
    else if (t < 64) bs[t] = bc22[e * 32 + (t - 32)];
    else if (t < 80) bs[t] = bc23[e * 16 + (t - 64)];
  }
  {
    const float4* __restrict__ src = (const float4*)(xt + n * 128 + sub * 32);
    float4 tmp[8];
#pragma unroll
    for (int j = 0; j < 8; ++j) tmp[j] = src[j];
#pragma unroll
    for (int j = 0; j < 8; ++j)
      *(float4*)(&xs_[tg][sub * 32 + 4 * j]) = tmp[j];
  }
  __syncthreads();

  const int wb1 = sub * 8;
  float a[8];
#pragma unroll
  for (int o = 0; o < 8; ++o) a[o] = bs[wb1 + o];
#pragma unroll
  for (int k = 0; k < 128; k += 4) {
    float x4[4];
    *(float4*)x4 = *(const float4*)(&xs_[tg][k]);
#pragma unroll
    for (int kk = 0; kk < 4; ++kk) {
      float w8[8];
      *(float4*)&w8[0] = *(const float4*)&w1s[(k + kk) * 32 + wb1];
      *(float4*)&w8[4] = *(const float4*)&w1s[(k + kk) * 32 + wb1 + 4];
#pragma unroll
      for (int o = 0; o < 8; ++o) a[o] = fmaf(x4[kk], w8[o], a[o]);
    }
  }
#pragma unroll
  for (int o = 0; o < 8; ++o) a[o] = a[o] > 0.f ? a[o] : 0.01f * a[o];

  float b[8];
#pragma unroll
  for (int o = 0; o < 8; ++o) b[o] = bs[32 + wb1 + o];
#pragma unroll
  for (int i = 0; i < 32; ++i) {
    const float hv = __shfl(a[i & 7], l0 + (i >> 3), 64);
    float w8[8];
    *(float4*)&w8[0] = *(const float4*)&w2s[i * 32 + wb1];
    *(float4*)&w8[4] = *(const float4*)&w2s[i * 32 + wb1 + 4];
#pragma unroll
    for (int o = 0; o < 8; ++o) b[o] = fmaf(hv, w8[o], b[o]);
  }
#pragma unroll
  for (int o = 0; o < 8; ++o) b[o] = b[o] > 0.f ? b[o] : 0.01f * b[o];

  float s[4];
#pragma unroll
  for (int j = 0; j < 4; ++j) s[j] = bs[64 + sub * 4 + j];
#pragma unroll
  for (int i = 0; i < 32; ++i) {
    const float hv = __shfl(b[i & 7], l0 + (i >> 3), 64);
    float w4[4];
    *(float4*)w4 = *(const float4*)&w3s[i * 16 + sub * 4];
#pragma unroll
    for (int j = 0; j < 4; ++j) s[j] = fmaf(hv, w4[j], s[j]);
  }

  float bv = s[0];
  int bi = sub * 4;
#pragma unroll
  for (int j = 1; j < 4; ++j) {
    if (s[j] > bv) { bv = s[j]; bi = sub * 4 + j; }
  }
#pragma unroll
  for (int d = 1; d < 4; d <<= 1) {
    const float ov = __shfl_xor(bv, d, 64);
    const int oi = __shfl_xor(bi, d, 64);
    if (ov > bv || (ov == bv && oi < bi)) { bv = ov; bi = oi; }
  }
  const int e12 = e * 16 + bi;
  if (valid && sub == 0) {
    e12a[n] = e12;
    atomicAdd(&lh[bi], 1);
  }
  __syncthreads();
  if (t < 16 && lh[t] > 0)
    atomicAdd(&cnt2[e * 16 + t], lh[t]);
}

// ---------------------------------------------------------------------------
// chain2 v5: LDS-weight-staged; descriptor from cnt2 (256 bins).
// ---------------------------------------------------------------------------
__global__ __launch_bounds__(256) void chain2_k(const float* __restrict__ xt,
    const int* __restrict__ ord2, const int* __restrict__ cnt2,
    const float* __restrict__ wr11, const float* __restrict__ br11,
    const float* __restrict__ wr12, const float* __restrict__ br12,
    const float* __restrict__ wr13, const float* __restrict__ br13,
    float* __restrict__ out) {
  __shared__ float w1s[4096];
  __shared__ float w2s[512];
  __shared__ float w3s[16];
  __shared__ float bs[49];
  __shared__ float xs_[64][132];
  __shared__ int sel[4];
  __shared__ int wsC[4], wsD[4];
  const int t = threadIdx.x;
  const int lane = t & 63, wvi = t >> 6;
  if (t == 0) sel[0] = -1;
  {
    const int cb = cnt2[t];
    const int nb = (cb + TPB - 1) / TPB;
    int ic = cb, id = nb;
    for (int d = 1; d < 64; d <<= 1) {
      const int uc = __shfl_up(ic, d, 64);
      const int ud = __shfl_up(id, d, 64);
      if (lane >= d) { ic += uc; id += ud; }
    }
    if (lane == 63) { wsC[wvi] = ic; wsD[wvi] = id; }
    __syncthreads();
    int bc = 0, bd = 0;
#pragma unroll
    for (int w2 = 0; w2 < 4; ++w2) {
      if (w2 < wvi) { bc += wsC[w2]; bd += wsD[w2]; }
    }
    ic += bc; id += bd;
    const int accB = id - nb, accO = ic - cb;
    if ((int)blockIdx.x >= accB && (int)blockIdx.x < accB + nb) {
      sel[0] = t; sel[1] = blockIdx.x - accB; sel[2] = accO; sel[3] = cb;
    }
  }
  __syncthreads();
  if (sel[0] < 0) return;
  const int e12   = __builtin_amdgcn_readfirstlane(sel[0]);
  const int chunk = __builtin_amdgcn_readfirstlane(sel[1]);
  const int offe  = __builtin_amdgcn_readfirstlane(sel[2]);
  const int cnt   = __builtin_amdgcn_readfirstlane(sel[3]);

  const int tg = t >> 2, sub = t & 3;
  const int l0 = (t & 63) & ~3;
  const int pos = chunk * TPB + tg;
  const bool valid = pos < cnt;
  const int n = valid ? ord2[offe + pos] : 0;

  {
    const float4* __restrict__ Wg1 = (const float4*)(wr11 + e12 * 4096);
#pragma unroll
    for (int j = 0; j < 4; ++j)
      *(float4*)&w1s[t * 4 + j * 1024] = Wg1[t + j * 256];
    if (t < 128) {
      const float4* __restrict__ Wg2 = (const float4*)(wr12 + e12 * 512);
      *(float4*)&w2s[t * 4] = Wg2[t];
    }
    if (t < 16) w3s[t] = wr13[e12 * 16 + t];
    if (t < 32) bs[t] = br11[e12 * 32 + t];
    else if (t < 48) bs[t] = br12[e12 * 16 + (t - 32)];
    else if (t == 48) bs[48] = br13[e12];
  }
  {
    const float4* __restrict__ src = (const float4*)(xt + n * 128 + sub * 32);
    float4 tmp[8];
#pragma unroll
    for (int j = 0; j < 8; ++j) tmp[j] = src[j];
#pragma unroll
    for (int j = 0; j < 8; ++j)
      *(float4*)(&xs_[tg][sub * 32 + 4 * j]) = tmp[j];
  }
  __syncthreads();

  const int wb1 = sub * 8;
  float a[8];
#pragma unroll
  for (int o = 0; o < 8; ++o) a[o] = bs[wb1 + o];
#pragma unroll
  for (int k = 0; k < 128; k += 4) {
    float x4[4];
    *(float4*)x4 = *(const float4*)(&xs_[tg][k]);
#pragma unroll
    for (int kk = 0; kk < 4; ++kk) {
      float w8[8];
      *(float4*)&w8[0] = *(const float4*)&w1s[(k + kk) * 32 + wb1];
      *(float4*)&w8[4] = *(const float4*)&w1s[(k + kk) * 32 + wb1 + 4];
#pragma unroll
      for (int o = 0; o < 8; ++o) a[o] = fmaf(x4[kk], w8[o], a[o]);
    }
  }
#pragma unroll
  for (int o = 0; o < 8; ++o) a[o] = a[o] > 0.f ? a[o] : 0.01f * a[o];

  float s[4];
#pragma unroll
  for (int j = 0; j < 4; ++j) s[j] = bs[32 + sub * 4 + j];
#pragma unroll
  for (int i = 0; i < 32; ++i) {
    const float hv = __shfl(a[i & 7], l0 + (i >> 3), 64);
    float w4[4];
    *(float4*)w4 = *(const float4*)&w2s[i * 16 + sub * 4];
#pragma unroll
    for (int j = 0; j < 4; ++j) s[j] = fmaf(hv, w4[j], s[j]);
  }
#pragma unroll
  for (int j = 0; j < 4; ++j) s[j] = s[j] > 0.f ? s[j] : 0.01f * s[j];

  float r = bs[48];
#pragma unroll
  for (int i = 0; i < 16; ++i) {
    const float hv = __shfl(s[i & 3], l0 + (i >> 2), 64);
    r = fmaf(hv, w3s[i], r);
  }

  if (valid && sub == 0) out[n] = ((float)e12 + r) * (1.0f / 256.0f);
}

// ---------------------------------------------------------------------------
extern "C" void kernel_launch(void* const* d_in, const int* in_sizes, int n_in,
                              void* d_out, int out_size, void* d_ws,
                              size_t ws_size, hipStream_t stream) {
  const float* x_in  = (const float*)d_in[0];
  const float* w_c11 = (const float*)d_in[1];
  const float* b_c11 = (const float*)d_in[2];
  const float* w_c12 = (const float*)d_in[3];
  const float* b_c12 = (const float*)d_in[4];
  const float* w_c13 = (const float*)d_in[5];
  const float* b_c13 = (const float*)d_in[6];
  const float* w_c21 = (const float*)d_in[7];
  const float* b_c21 = (const float*)d_in[8];
  const float* w_c22 = (const float*)d_in[9];
  const float* b_c22 = (const float*)d_in[10];
  const float* w_c23 = (const float*)d_in[11];
  const float* b_c23 = (const float*)d_in[12];
  const float* w_r11 = (const float*)d_in[13];
  const float* b_r11 = (const float*)d_in[14];
  const float* w_r12 = (const float*)d_in[15];
  const float* b_r12 = (const float*)d_in[16];
  const float* w_r13 = (const float*)d_in[17];
  const float* b_r13 = (const float*)d_in[18];

  float* out = (float*)d_out;   // [0..N): x_real (token order), [N..2N): mask

  float* R0 = (float*)d_ws;
  float* R1 = R0 + 128 * NPIX;
  float* R2 = R1 + 128 * NPIX;

  float* xt = R0;
  unsigned char* inds1 = (unsigned char*)R2;   // N bytes
  float* wT1 = R2 + 12288;
  float* wT2 = wT1 + 16384;
  int* S = (int*)R2 + 45056;

  int* cnt1 = S;             // 16
  int* cur1 = S + 16;        // 16
  int* cnt2 = S + 1088;      // 256
  int* cur2 = S + 1344;      // 256

  int* ib   = (int*)R1;
  int* ord1 = ib;            // N
  int* ord2 = ib + NPIX;     // N
  int* e12a = ib + 2 * NPIX; // N

  wtrans2_k<<<32, 256, 0, stream>>>(w_c11, wT1, w_c12, wT2, S);
  convfused_k<<<NPIX / 64, 512, 0, stream>>>(x_in, wT1, b_c11, wT2, b_c12,
      w_c13, b_c13, inds1, out + NPIX, cnt1, xt);
  scatter_k<unsigned char><<<NPIX / 256, 256, 0, stream>>>(inds1, cnt1, cur1,
                                                           ord1, 16);
  chain1_k<<<NPIX / TPB + 16, 256, 0, stream>>>(xt, ord1, cnt1,
      w_c21, b_c21, w_c22, b_c22, w_c23, b_c23, e12a, cnt2);
  scatter_k<int><<<NPIX / 256, 256, 0, stream>>>(e12a, cnt2, cur2, ord2, 256);
  chain2_k<<<NPIX / TPB + 256, 256, 0, stream>>>(xt, ord2, cnt2,
      w_r11, b_r11, w_r12, b_r12, w_r13, b_r13, out);
}